// Round 6
// baseline (559.864 us; speedup 1.0000x reference)
//
#include <hip/hip_runtime.h>
#include <math.h>

typedef __attribute__((ext_vector_type(8))) __bf16 bf16x8;
typedef __attribute__((ext_vector_type(8))) unsigned short u16x8;
typedef __attribute__((ext_vector_type(4))) unsigned short u16x4;
typedef __attribute__((ext_vector_type(4))) float f32x4;

namespace {
constexpr int EMB = 256;
constexpr int HD  = 128;
constexpr int FF  = 1024;
constexpr float EPSV = 1e-5f;
constexpr int M   = 128;      // rows per block = 4 sequences x 32

// fragment-ordered weight regions in ws (ushort elements).
// frag = (nt*KK + kk); elem = (frag*64 + lane)*8 + j  holds
// W^T[nt*16 + (lane&15)][kk*32 + (lane>>4)*8 + j]
constexpr int WS_QKV = 0;        // 24 nt x 8 kk x 512
constexpr int WS_O   = 98304;    // 16 nt x 4 kk x 512
constexpr int WS_1   = 131072;   // 64 nt x 8 kk x 512
constexpr int WS_2   = 393216;   // 16 nt x 32 kk x 512

__device__ __forceinline__ unsigned short f32_to_bf16(float f) {
    unsigned int u = __builtin_bit_cast(unsigned int, f);
    u += 0x7FFFu + ((u >> 16) & 1u);           // RNE; inputs finite
    return (unsigned short)(u >> 16);
}
__device__ __forceinline__ float bf16_to_f32(unsigned short h) {
    return __builtin_bit_cast(float, ((unsigned int)h) << 16);
}
__device__ __forceinline__ f32x4 mfma16(u16x8 a, u16x8 b, f32x4 c) {
    return __builtin_amdgcn_mfma_f32_16x16x32_bf16(
        __builtin_bit_cast(bf16x8, a), __builtin_bit_cast(bf16x8, b), c, 0, 0, 0);
}
// byte-XOR swizzle: spreads row-starts over banks (~2-way max), 16B-safe
__device__ __forceinline__ int swzB(int row) { return ((row & 7) << 4) | ((row & 8) << 2); }

__device__ __forceinline__ u16x8 ldsA256(const unsigned short* base, int row, int k0) {
    int byte = (row * 256 + k0 * 2) ^ swzB(row);
    return *(const u16x8*)((const char*)base + byte);
}
__device__ __forceinline__ u16x8 ldsA512(const unsigned short* base, int row, int k0) {
    int byte = (row * 512 + k0 * 2) ^ swzB(row);
    return *(const u16x8*)((const char*)base + byte);
}
__device__ __forceinline__ u16x8 ldgF(const unsigned short* base, int frag, int lane) {
    return *(const u16x8*)(base + ((size_t)frag * 64 + lane) * 8);   // 1KB/wave, coalesced
}
} // namespace

// one-shot weight convert: fp32 -> bf16 fragment-ordered layout in ws (unchanged)
__global__ __launch_bounds__(256) void wconv(
    const float* __restrict__ Wq, const float* __restrict__ Wk, const float* __restrict__ Wv,
    const float* __restrict__ Wo, const float* __restrict__ W1, const float* __restrict__ W2,
    unsigned short* __restrict__ ws) {
    int e = blockIdx.x * 256 + threadIdx.x;     // 0..655359
    int j, lane, kk, nt, n, k;
    float v;
    if (e < WS_O) {                             // QKV, K=256, 24 nt
        int t = e; j = t & 7; lane = (t >> 3) & 63; int r2 = t >> 9;
        kk = r2 & 7; nt = r2 >> 3;
        n = nt * 16 + (lane & 15); k = kk * 32 + (lane >> 4) * 8 + j;
        const float* W = (n < 128) ? Wq : ((n < 256) ? Wk : Wv);
        v = W[k * HD + (n & 127)];
    } else if (e < WS_1) {                      // Wo, K=128, 16 nt
        int t = e - WS_O; j = t & 7; lane = (t >> 3) & 63; int r2 = t >> 9;
        kk = r2 & 3; nt = r2 >> 2;
        n = nt * 16 + (lane & 15); k = kk * 32 + (lane >> 4) * 8 + j;
        v = Wo[k * EMB + n];
    } else if (e < WS_2) {                      // W1, K=256, 64 nt
        int t = e - WS_1; j = t & 7; lane = (t >> 3) & 63; int r2 = t >> 9;
        kk = r2 & 7; nt = r2 >> 3;
        n = nt * 16 + (lane & 15); k = kk * 32 + (lane >> 4) * 8 + j;
        v = W1[k * FF + n];
    } else {                                    // W2, K=1024, 16 nt
        int t = e - WS_2; j = t & 7; lane = (t >> 3) & 63; int r2 = t >> 9;
        kk = r2 & 31; nt = r2 >> 5;
        n = nt * 16 + (lane & 15); k = kk * 32 + (lane >> 4) * 8 + j;
        v = W2[k * EMB + n];
    }
    ws[e] = f32_to_bf16(v);
}

// one block = 4 sequences (M=128 rows). 8 waves (512 thr) -> 2 waves/SIMD at
// 1 block/CU (160KB LDS). launch_bounds(512,2) caps VGPR at 256: widest phase
// ~200 live regs, no spills. B-fragments read ~once per block.
__global__ __launch_bounds__(512, 2) void attn_block_mfma(
    const float* __restrict__ X, const float* __restrict__ ln_g, const float* __restrict__ ln_b,
    const float* __restrict__ bq, const float* __restrict__ bk, const float* __restrict__ bv,
    const float* __restrict__ bo, const float* __restrict__ b1, const float* __restrict__ b2,
    const unsigned short* __restrict__ ws, float* __restrict__ out) {
    // LDS map (160KB):
    //   hbuf [128][256] b16 rb512 @0      (h after LN1; h2 after LN2)      64KB
    //   Qb   [128][128] b16 rb256 @64K    (Q; ctx after attn; fch in FFN)  32KB
    //   KVb  K,V [128][128] rb256 @96K    (X1 [128][256] rb512 after P4)   64KB
    __shared__ __attribute__((aligned(16))) char smem[163840];
    unsigned short* hbuf = (unsigned short*)smem;
    unsigned short* Qb   = (unsigned short*)(smem + 65536);
    char* Kc             = smem + 98304;
    char* Vc             = smem + 131072;
    unsigned short* X1b  = (unsigned short*)(smem + 98304);   // overlays K|V
    unsigned short* fch  = Qb;                                 // overlays Q/ctx

    const unsigned short* WTqkv = ws + WS_QKV;
    const unsigned short* WTo   = ws + WS_O;
    const unsigned short* WT1   = ws + WS_1;
    const unsigned short* WT2   = ws + WS_2;

    const int tid  = threadIdx.x;
    const int wv   = tid >> 6;                  // 0..7
    const int lane = tid & 63;
    const int lr   = lane & 15;
    const int lh   = lane >> 4;
    const int row0 = blockIdx.x * M;            // global row base (4 seqs)
    const f32x4 Z  = {0.f, 0.f, 0.f, 0.f};

    // ---- P1: LN1 from global X -> hbuf (bf16, swz). 8 thr/row, 2 passes ----
    {
        const int r = tid >> 3, sub = tid & 7;  // r: 0..63
        #pragma unroll 1
        for (int pass = 0; pass < 2; ++pass) {
            int rr = pass * 64 + r;
            const float* xr = X + (size_t)(row0 + rr) * EMB;
            float4 vv[8];
            float s = 0.f, ss = 0.f;
            #pragma unroll
            for (int j = 0; j < 8; ++j) {
                float4 v = *(const float4*)&xr[sub * 4 + j * 32];
                vv[j] = v;
                s  += (v.x + v.y) + (v.z + v.w);
                ss += (v.x * v.x + v.y * v.y) + (v.z * v.z + v.w * v.w);
            }
            #pragma unroll
            for (int w = 1; w < 8; w <<= 1) { s += __shfl_xor(s, w, 64); ss += __shfl_xor(ss, w, 64); }
            float mu  = s * (1.f / EMB);
            float inv = rsqrtf(fmaxf(ss * (1.f / EMB) - mu * mu, 0.f) + EPSV);
            #pragma unroll
            for (int j = 0; j < 8; ++j) {
                int c = sub * 4 + j * 32;
                float4 v = vv[j];
                float4 g4 = *(const float4*)&ln_g[c];
                float4 b4 = *(const float4*)&ln_b[c];
                u16x4 pk;
                pk[0] = f32_to_bf16((v.x - mu) * inv * g4.x + b4.x);
                pk[1] = f32_to_bf16((v.y - mu) * inv * g4.y + b4.y);
                pk[2] = f32_to_bf16((v.z - mu) * inv * g4.z + b4.z);
                pk[3] = f32_to_bf16((v.w - mu) * inv * g4.w + b4.w);
                *(u16x4*)((char*)hbuf + ((rr * 512 + c * 2) ^ swzB(rr))) = pk;
            }
        }
    }
    __syncthreads();

    // ---- P2: QKV = h @ Wqkv + b.  wave owns 3 nt (of 24) x all 8 mt ----
    {
        #pragma unroll 1
        for (int mtp = 0; mtp < 8; mtp += 4) {
            u16x8 afr[4][8];
            #pragma unroll
            for (int m = 0; m < 4; ++m)
                #pragma unroll
                for (int kk = 0; kk < 8; ++kk)
                    afr[m][kk] = ldsA512(hbuf, (mtp + m) * 16 + lr, kk * 32 + lh * 8);
            #pragma unroll 1
            for (int i = 0; i < 3; ++i) {
                int nt = wv * 3 + i;
                u16x8 bfr[8];
                #pragma unroll
                for (int kk = 0; kk < 8; ++kk) bfr[kk] = ldgF(WTqkv, nt * 8 + kk, lane);
                int gcol = nt * 16 + lr;
                int mat = gcol >> 7, c = gcol & 127;
                const float* bias = (mat == 0) ? bq : ((mat == 1) ? bk : bv);
                float bc = bias[c];
                char* regbase = smem + 65536 + mat * 32768;
                #pragma unroll
                for (int m = 0; m < 4; ++m) {
                    f32x4 e = Z, o = Z;
                    #pragma unroll
                    for (int kk = 0; kk < 8; kk += 2) {
                        e = mfma16(afr[m][kk], bfr[kk], e);
                        o = mfma16(afr[m][kk + 1], bfr[kk + 1], o);
                    }
                    f32x4 a = e + o;
                    #pragma unroll
                    for (int reg = 0; reg < 4; ++reg) {
                        int r0 = (mtp + m) * 16 + lh * 4 + reg;
                        *(unsigned short*)(regbase + ((r0 * 256 + c * 2) ^ swzB(r0))) =
                            f32_to_bf16(a[reg] + bc);
                    }
                }
            }
        }
    }
    __syncthreads();

    // ---- P3: attention (VALU). thread=(sh,head,q); 2 seqs serial. ctx -> Qb ----
    {
        const int hd = (tid >> 5) & 7, q = tid & 31, sh = tid >> 8;  // sh: 0/1
        #pragma unroll 1
        for (int si = 0; si < 2; ++si) {
            int s = sh * 2 + si;
            int row = s * 32 + q;
            int by0 = (row * 256 + hd * 32) ^ swzB(row);
            int by1 = (row * 256 + hd * 32 + 16) ^ swzB(row);
            float qreg[16];
            {
                u16x8 a = *(const u16x8*)((const char*)Qb + by0);
                u16x8 b_ = *(const u16x8*)((const char*)Qb + by1);
                #pragma unroll
                for (int j = 0; j < 8; ++j) { qreg[j] = bf16_to_f32(a[j]); qreg[8 + j] = bf16_to_f32(b_[j]); }
            }
            float p[32]; float mmax = -1e30f;
            #pragma unroll
            for (int k = 0; k < 32; ++k) {
                int rk = s * 32 + k;
                int kb0 = (rk * 256 + hd * 32) ^ swzB(rk);
                int kb1 = (rk * 256 + hd * 32 + 16) ^ swzB(rk);
                u16x8 a = *(const u16x8*)(Kc + kb0);
                u16x8 b_ = *(const u16x8*)(Kc + kb1);
                float s_ = 0.f;
                #pragma unroll
                for (int j = 0; j < 8; ++j)
                    s_ += qreg[j] * bf16_to_f32(a[j]) + qreg[8 + j] * bf16_to_f32(b_[j]);
                s_ *= 0.25f;
                p[k] = s_;
                if (k <= q) mmax = fmaxf(mmax, s_);
            }
            float den = 0.f;
            #pragma unroll
            for (int k = 0; k < 32; ++k) {
                float e = (k <= q) ? __expf(p[k] - mmax) : 0.f;
                p[k] = e; den += e;
            }
            float rd = 1.f / den;
            float ctx[16];
            #pragma unroll
            for (int j = 0; j < 16; ++j) ctx[j] = 0.f;
            #pragma unroll
            for (int k = 0; k < 32; ++k) {
                int rk = s * 32 + k;
                int vb0 = (rk * 256 + hd * 32) ^ swzB(rk);
                int vb1 = (rk * 256 + hd * 32 + 16) ^ swzB(rk);
                u16x8 a = *(const u16x8*)(Vc + vb0);
                u16x8 b_ = *(const u16x8*)(Vc + vb1);
                float pk_ = p[k];
                #pragma unroll
                for (int j = 0; j < 8; ++j) { ctx[j] += pk_ * bf16_to_f32(a[j]); ctx[8 + j] += pk_ * bf16_to_f32(b_[j]); }
            }
            u16x8 o0, o1;
            #pragma unroll
            for (int j = 0; j < 8; ++j) { o0[j] = f32_to_bf16(ctx[j] * rd); o1[j] = f32_to_bf16(ctx[8 + j] * rd); }
            *(u16x8*)((char*)Qb + by0) = o0;
            *(u16x8*)((char*)Qb + by1) = o1;
        }
    }
    __syncthreads();

    // ---- P4: X1 = ctx @ Wo + bo + X(reload global) -> X1b bf16 (overlay K|V) ----
    {
        #pragma unroll 1
        for (int mtp = 0; mtp < 8; mtp += 4) {
            u16x8 afr[4][4];
            #pragma unroll
            for (int m = 0; m < 4; ++m)
                #pragma unroll
                for (int kk = 0; kk < 4; ++kk)
                    afr[m][kk] = ldsA256(Qb, (mtp + m) * 16 + lr, kk * 32 + lh * 8);
            #pragma unroll
            for (int i = 0; i < 2; ++i) {
                int nt = wv * 2 + i;
                u16x8 bfr[4];
                #pragma unroll
                for (int kk = 0; kk < 4; ++kk) bfr[kk] = ldgF(WTo, nt * 4 + kk, lane);
                int col = nt * 16 + lr;
                float bc = bo[col];
                #pragma unroll
                for (int m = 0; m < 4; ++m) {
                    f32x4 e = Z, o = Z;
                    e = mfma16(afr[m][0], bfr[0], e);
                    o = mfma16(afr[m][1], bfr[1], o);
                    e = mfma16(afr[m][2], bfr[2], e);
                    o = mfma16(afr[m][3], bfr[3], o);
                    f32x4 a = e + o;
                    #pragma unroll
                    for (int reg = 0; reg < 4; ++reg) {
                        int r0 = (mtp + m) * 16 + lh * 4 + reg;
                        float xv = X[(size_t)(row0 + r0) * EMB + col];
                        *(unsigned short*)((char*)X1b + ((r0 * 512 + col * 2) ^ swzB(r0))) =
                            f32_to_bf16(a[reg] + bc + xv);
                    }
                }
            }
        }
    }
    __syncthreads();

    // ---- P5: LN2 from X1b (bf16) -> hbuf ----
    {
        const int r = tid >> 3, sub = tid & 7;
        #pragma unroll 1
        for (int pass = 0; pass < 2; ++pass) {
            int rr = pass * 64 + r;
            float vals[32];
            float s = 0.f, ss = 0.f;
            #pragma unroll
            for (int j = 0; j < 8; ++j) {
                int c = sub * 4 + j * 32;
                u16x4 hv = *(const u16x4*)((const char*)X1b + ((rr * 512 + c * 2) ^ swzB(rr)));
                #pragma unroll
                for (int t = 0; t < 4; ++t) {
                    float f = bf16_to_f32(hv[t]);
                    vals[j * 4 + t] = f;
                    s += f; ss += f * f;
                }
            }
            #pragma unroll
            for (int w = 1; w < 8; w <<= 1) { s += __shfl_xor(s, w, 64); ss += __shfl_xor(ss, w, 64); }
            float mu  = s * (1.f / EMB);
            float inv = rsqrtf(fmaxf(ss * (1.f / EMB) - mu * mu, 0.f) + EPSV);
            #pragma unroll
            for (int j = 0; j < 8; ++j) {
                int c = sub * 4 + j * 32;
                float4 g4 = *(const float4*)&ln_g[c];
                float4 b4 = *(const float4*)&ln_b[c];
                u16x4 pk;
                pk[0] = f32_to_bf16((vals[j * 4 + 0] - mu) * inv * g4.x + b4.x);
                pk[1] = f32_to_bf16((vals[j * 4 + 1] - mu) * inv * g4.y + b4.y);
                pk[2] = f32_to_bf16((vals[j * 4 + 2] - mu) * inv * g4.z + b4.z);
                pk[3] = f32_to_bf16((vals[j * 4 + 3] - mu) * inv * g4.w + b4.w);
                *(u16x4*)((char*)hbuf + ((rr * 512 + c * 2) ^ swzB(rr))) = pk;
            }
        }
    }
    __syncthreads();

    // ---- P6: FFN in 8 chunks of 128 FF cols. fch overlays Q. acc2 persistent ----
    {
        f32x4 acc2[8][2];
        #pragma unroll
        for (int mt = 0; mt < 8; ++mt) { acc2[mt][0] = Z; acc2[mt][1] = Z; }

        #pragma unroll 1
        for (int ch = 0; ch < 8; ++ch) {
            // FFN1: relu(h2 @ W1[:, chunk] + b1) -> fch.  wave owns 1 fn of 8.
            u16x8 bAll[8];
            {
                int fn = ch * 8 + wv;
                #pragma unroll
                for (int kk = 0; kk < 8; ++kk) bAll[kk] = ldgF(WT1, fn * 8 + kk, lane);
            }
            {
                int fn = ch * 8 + wv;
                float bc = b1[fn * 16 + lr];
                int cc = wv * 16 + lr;
                #pragma unroll 1
                for (int mtp = 0; mtp < 8; mtp += 2) {
                    u16x8 afr[2][8];
                    #pragma unroll
                    for (int m = 0; m < 2; ++m)
                        #pragma unroll
                        for (int kk = 0; kk < 8; ++kk)
                            afr[m][kk] = ldsA512(hbuf, (mtp + m) * 16 + lr, kk * 32 + lh * 8);
                    #pragma unroll
                    for (int m = 0; m < 2; ++m) {
                        f32x4 e = Z, o = Z;
                        #pragma unroll
                        for (int kk = 0; kk < 8; kk += 2) {
                            e = mfma16(afr[m][kk], bAll[kk], e);
                            o = mfma16(afr[m][kk + 1], bAll[kk + 1], o);
                        }
                        f32x4 a = e + o;
                        #pragma unroll
                        for (int reg = 0; reg < 4; ++reg) {
                            int r0 = (mtp + m) * 16 + lh * 4 + reg;
                            *(unsigned short*)((char*)fch + ((r0 * 256 + cc * 2) ^ swzB(r0))) =
                                f32_to_bf16(fmaxf(a[reg] + bc, 0.f));
                        }
                    }
                }
            }
            __syncthreads();
            // FFN2: acc2 += fch @ W2[chunk-slice].  wave owns 2 nt of 16.
            u16x8 b2f[2][4];
            #pragma unroll
            for (int i = 0; i < 2; ++i)
                #pragma unroll
                for (int kk = 0; kk < 4; ++kk)
                    b2f[i][kk] = ldgF(WT2, (wv * 2 + i) * 32 + ch * 4 + kk, lane);
            #pragma unroll
            for (int mt = 0; mt < 8; ++mt) {
                u16x8 afr[4];
                #pragma unroll
                for (int kk = 0; kk < 4; ++kk)
                    afr[kk] = ldsA256(fch, mt * 16 + lr, kk * 32 + lh * 8);
                #pragma unroll
                for (int i = 0; i < 2; ++i) {
                    f32x4 t = acc2[mt][i];
                    t = mfma16(afr[0], b2f[i][0], t);
                    t = mfma16(afr[1], b2f[i][1], t);
                    t = mfma16(afr[2], b2f[i][2], t);
                    t = mfma16(afr[3], b2f[i][3], t);
                    acc2[mt][i] = t;
                }
            }
            __syncthreads();
        }
        // epilogue: out = acc2 + b2 + X1 (from LDS bf16)
        float* outp = out + (size_t)row0 * EMB;
        #pragma unroll
        for (int i = 0; i < 2; ++i) {
            int col = (wv * 2 + i) * 16 + lr;
            float bc = b2[col];
            #pragma unroll
            for (int mt = 0; mt < 8; ++mt) {
                #pragma unroll
                for (int reg = 0; reg < 4; ++reg) {
                    int r0 = mt * 16 + lh * 4 + reg;
                    float x1 = bf16_to_f32(*(const unsigned short*)((const char*)X1b +
                                          ((r0 * 512 + col * 2) ^ swzB(r0))));
                    outp[(size_t)r0 * EMB + col] = acc2[mt][i][reg] + bc + x1;
                }
            }
        }
    }
}

extern "C" void kernel_launch(void* const* d_in, const int* in_sizes, int n_in,
                              void* d_out, int out_size, void* d_ws, size_t ws_size,
                              hipStream_t stream) {
    const float* X    = (const float*)d_in[0];
    const float* ln_g = (const float*)d_in[1];
    const float* ln_b = (const float*)d_in[2];
    const float* Wq   = (const float*)d_in[3];
    const float* bq   = (const float*)d_in[4];
    const float* Wk   = (const float*)d_in[5];
    const float* bk   = (const float*)d_in[6];
    const float* Wv   = (const float*)d_in[7];
    const float* bv   = (const float*)d_in[8];
    const float* Wo   = (const float*)d_in[9];
    const float* bo   = (const float*)d_in[10];
    const float* W1   = (const float*)d_in[11];
    const float* b1   = (const float*)d_in[12];
    const float* W2   = (const float*)d_in[13];
    const float* b2   = (const float*)d_in[14];
    unsigned short* ws = (unsigned short*)d_ws;
    float* O = (float*)d_out;

    wconv<<<2560, 256, 0, stream>>>(Wq, Wk, Wv, Wo, W1, W2, ws);
    attn_block_mfma<<<1024, 512, 0, stream>>>(X, ln_g, ln_b, bq, bk, bv, bo, b1, b2, ws, O);
}

// Round 7
// 431.599 us; speedup vs baseline: 1.2972x; 1.2972x over previous
//
#include <hip/hip_runtime.h>
#include <math.h>

typedef __attribute__((ext_vector_type(8))) __bf16 bf16x8;
typedef __attribute__((ext_vector_type(8))) unsigned short u16x8;
typedef __attribute__((ext_vector_type(4))) unsigned short u16x4;
typedef __attribute__((ext_vector_type(4))) float f32x4;

namespace {
constexpr int EMB = 256;
constexpr int HD  = 128;
constexpr int FF  = 1024;
constexpr float EPSV = 1e-5f;
constexpr int M   = 64;       // rows per block = 2 sequences x 32

// fragment-ordered weight regions in ws (ushort elements).
// frag = (nt*KK + kk); elem = (frag*64 + lane)*8 + j  holds
// W^T[nt*16 + (lane&15)][kk*32 + (lane>>4)*8 + j]
constexpr int WS_QKV = 0;        // 24 nt x 8 kk x 512
constexpr int WS_O   = 98304;    // 16 nt x 4 kk x 512
constexpr int WS_1   = 131072;   // 64 nt x 8 kk x 512
constexpr int WS_2   = 393216;   // 16 nt x 32 kk x 512

__device__ __forceinline__ unsigned short f32_to_bf16(float f) {
    unsigned int u = __builtin_bit_cast(unsigned int, f);
    u += 0x7FFFu + ((u >> 16) & 1u);           // RNE; inputs finite
    return (unsigned short)(u >> 16);
}
__device__ __forceinline__ float bf16_to_f32(unsigned short h) {
    return __builtin_bit_cast(float, ((unsigned int)h) << 16);
}
__device__ __forceinline__ f32x4 mfma16(u16x8 a, u16x8 b, f32x4 c) {
    return __builtin_amdgcn_mfma_f32_16x16x32_bf16(
        __builtin_bit_cast(bf16x8, a), __builtin_bit_cast(bf16x8, b), c, 0, 0, 0);
}
// verified G4 swizzle: bijective within each 8-row stripe, 16B-granular
__device__ __forceinline__ int swzB(int row) { return (row & 7) << 4; }

__device__ __forceinline__ u16x8 ldsA256(const unsigned short* base, int row, int k0) {
    int byte = (row * 256 + k0 * 2) ^ swzB(row);
    return *(const u16x8*)((const char*)base + byte);
}
__device__ __forceinline__ u16x8 ldsA512(const unsigned short* base, int row, int k0) {
    int byte = (row * 512 + k0 * 2) ^ swzB(row);
    return *(const u16x8*)((const char*)base + byte);
}
__device__ __forceinline__ u16x8 ldgF(const unsigned short* base, int frag, int lane) {
    return *(const u16x8*)(base + ((size_t)frag * 64 + lane) * 8);   // 1KB/wave, coalesced
}
} // namespace

// one-shot weight convert: fp32 -> bf16 fragment-ordered layout in ws (unchanged)
__global__ __launch_bounds__(256) void wconv(
    const float* __restrict__ Wq, const float* __restrict__ Wk, const float* __restrict__ Wv,
    const float* __restrict__ Wo, const float* __restrict__ W1, const float* __restrict__ W2,
    unsigned short* __restrict__ ws) {
    int e = blockIdx.x * 256 + threadIdx.x;     // 0..655359
    int j, lane, kk, nt, n, k;
    float v;
    if (e < WS_O) {                             // QKV, K=256, 24 nt
        int t = e; j = t & 7; lane = (t >> 3) & 63; int r2 = t >> 9;
        kk = r2 & 7; nt = r2 >> 3;
        n = nt * 16 + (lane & 15); k = kk * 32 + (lane >> 4) * 8 + j;
        const float* W = (n < 128) ? Wq : ((n < 256) ? Wk : Wv);
        v = W[k * HD + (n & 127)];
    } else if (e < WS_1) {                      // Wo, K=128, 16 nt
        int t = e - WS_O; j = t & 7; lane = (t >> 3) & 63; int r2 = t >> 9;
        kk = r2 & 3; nt = r2 >> 2;
        n = nt * 16 + (lane & 15); k = kk * 32 + (lane >> 4) * 8 + j;
        v = Wo[k * EMB + n];
    } else if (e < WS_2) {                      // W1, K=256, 64 nt
        int t = e - WS_1; j = t & 7; lane = (t >> 3) & 63; int r2 = t >> 9;
        kk = r2 & 7; nt = r2 >> 3;
        n = nt * 16 + (lane & 15); k = kk * 32 + (lane >> 4) * 8 + j;
        v = W1[k * FF + n];
    } else {                                    // W2, K=1024, 16 nt
        int t = e - WS_2; j = t & 7; lane = (t >> 3) & 63; int r2 = t >> 9;
        kk = r2 & 31; nt = r2 >> 5;
        n = nt * 16 + (lane & 15); k = kk * 32 + (lane >> 4) * 8 + j;
        v = W2[k * EMB + n];
    }
    ws[e] = f32_to_bf16(v);
}

// one block = 2 sequences (M=64). 4 waves, 80KB LDS -> 2 blocks/CU (8 waves/CU,
// 2 waves/EU) with independent barriers. launch_bounds(256,1): VGPR budget 512,
// compiler lands ~200 (<=256 so both blocks stay resident), no spills.
__global__ __launch_bounds__(256, 1) void attn_block_mfma(
    const float* __restrict__ X, const float* __restrict__ ln_g, const float* __restrict__ ln_b,
    const float* __restrict__ bq, const float* __restrict__ bk, const float* __restrict__ bv,
    const float* __restrict__ bo, const float* __restrict__ b1, const float* __restrict__ b2,
    const unsigned short* __restrict__ ws, float* __restrict__ out) {
    // LDS map (80KB):
    //   hbuf [64][256] b16 rb512 @0       (h after LN1; h2 after LN2)   32KB
    //   Qb   [64][128] b16 rb256 @32K     (Q; ctx; fch in FFN)          16KB
    //   Kc   [64][128] b16 rb256 @48K     (K; X1b low half after P4)    16KB
    //   Vc   [64][128] b16 rb256 @64K     (V; X1b high half after P4)   16KB
    __shared__ __attribute__((aligned(16))) char smem[81920];
    unsigned short* hbuf = (unsigned short*)smem;
    unsigned short* Qb   = (unsigned short*)(smem + 32768);
    char* Kc             = smem + 49152;
    char* Vc             = smem + 65536;
    unsigned short* X1b  = (unsigned short*)(smem + 49152);   // [64][256] rb512, overlays K|V
    unsigned short* fch  = Qb;                                // overlays Q/ctx

    const unsigned short* WTqkv = ws + WS_QKV;
    const unsigned short* WTo   = ws + WS_O;
    const unsigned short* WT1   = ws + WS_1;
    const unsigned short* WT2   = ws + WS_2;

    const int tid  = threadIdx.x;
    const int wv   = tid >> 6;                  // 0..3
    const int lane = tid & 63;
    const int lr   = lane & 15;
    const int lh   = lane >> 4;
    const int row0 = blockIdx.x * M;            // global row base (2 seqs)
    const f32x4 Z  = {0.f, 0.f, 0.f, 0.f};

    // ---- P1: LN1 from global X -> hbuf (bf16, swz). 8 thr/row, 2 passes ----
    {
        const int r = tid >> 3, sub = tid & 7;  // r: 0..31
        #pragma unroll 1
        for (int pass = 0; pass < 2; ++pass) {
            int rr = pass * 32 + r;
            const float* xr = X + (size_t)(row0 + rr) * EMB;
            float4 vv[8];
            float s = 0.f, ss = 0.f;
            #pragma unroll
            for (int j = 0; j < 8; ++j) {
                float4 v = *(const float4*)&xr[sub * 4 + j * 32];
                vv[j] = v;
                s  += (v.x + v.y) + (v.z + v.w);
                ss += (v.x * v.x + v.y * v.y) + (v.z * v.z + v.w * v.w);
            }
            #pragma unroll
            for (int w = 1; w < 8; w <<= 1) { s += __shfl_xor(s, w, 64); ss += __shfl_xor(ss, w, 64); }
            float mu  = s * (1.f / EMB);
            float inv = rsqrtf(fmaxf(ss * (1.f / EMB) - mu * mu, 0.f) + EPSV);
            #pragma unroll
            for (int j = 0; j < 8; ++j) {
                int c = sub * 4 + j * 32;
                float4 v = vv[j];
                float4 g4 = *(const float4*)&ln_g[c];
                float4 b4 = *(const float4*)&ln_b[c];
                u16x4 pk;
                pk[0] = f32_to_bf16((v.x - mu) * inv * g4.x + b4.x);
                pk[1] = f32_to_bf16((v.y - mu) * inv * g4.y + b4.y);
                pk[2] = f32_to_bf16((v.z - mu) * inv * g4.z + b4.z);
                pk[3] = f32_to_bf16((v.w - mu) * inv * g4.w + b4.w);
                *(u16x4*)((char*)hbuf + ((rr * 512 + c * 2) ^ swzB(rr))) = pk;
            }
        }
    }
    __syncthreads();

    // ---- P2: QKV = h @ Wqkv + b.  wave: 6 nt (of 24) x 4 mt in 2 passes ----
    {
        #pragma unroll 1
        for (int mtp = 0; mtp < 4; mtp += 2) {
            u16x8 afr[2][8];
            #pragma unroll
            for (int m = 0; m < 2; ++m)
                #pragma unroll
                for (int kk = 0; kk < 8; ++kk)
                    afr[m][kk] = ldsA512(hbuf, (mtp + m) * 16 + lr, kk * 32 + lh * 8);
            #pragma unroll 1
            for (int i = 0; i < 6; ++i) {
                int nt = wv * 6 + i;
                u16x8 bfr[8];
                #pragma unroll
                for (int kk = 0; kk < 8; ++kk) bfr[kk] = ldgF(WTqkv, nt * 8 + kk, lane);
                int gcol = nt * 16 + lr;
                int mat = gcol >> 7, c = gcol & 127;
                const float* bias = (mat == 0) ? bq : ((mat == 1) ? bk : bv);
                float bc = bias[c];
                char* regbase = smem + 32768 + mat * 16384;
                #pragma unroll
                for (int m = 0; m < 2; ++m) {
                    f32x4 e = Z, o = Z;
                    #pragma unroll
                    for (int kk = 0; kk < 8; kk += 2) {
                        e = mfma16(afr[m][kk], bfr[kk], e);
                        o = mfma16(afr[m][kk + 1], bfr[kk + 1], o);
                    }
                    f32x4 a = e + o;
                    #pragma unroll
                    for (int reg = 0; reg < 4; ++reg) {
                        int r0 = (mtp + m) * 16 + lh * 4 + reg;
                        *(unsigned short*)(regbase + ((r0 * 256 + c * 2) ^ swzB(r0))) =
                            f32_to_bf16(a[reg] + bc);
                    }
                }
            }
        }
    }
    __syncthreads();

    // ---- P3: attention (VALU). thread=(head,q); 2 seqs serial. ctx -> Qb ----
    {
        const int hd = (tid >> 5) & 7, q = tid & 31;
        #pragma unroll 1
        for (int s = 0; s < 2; ++s) {
            int row = s * 32 + q;
            int by0 = (row * 256 + hd * 32) ^ swzB(row);
            int by1 = (row * 256 + hd * 32 + 16) ^ swzB(row);
            float qreg[16];
            {
                u16x8 a = *(const u16x8*)((const char*)Qb + by0);
                u16x8 b_ = *(const u16x8*)((const char*)Qb + by1);
                #pragma unroll
                for (int j = 0; j < 8; ++j) { qreg[j] = bf16_to_f32(a[j]); qreg[8 + j] = bf16_to_f32(b_[j]); }
            }
            float p[32]; float mmax = -1e30f;
            #pragma unroll
            for (int k = 0; k < 32; ++k) {
                int rk = s * 32 + k;
                int kb0 = (rk * 256 + hd * 32) ^ swzB(rk);
                int kb1 = (rk * 256 + hd * 32 + 16) ^ swzB(rk);
                u16x8 a = *(const u16x8*)(Kc + kb0);
                u16x8 b_ = *(const u16x8*)(Kc + kb1);
                float s_ = 0.f;
                #pragma unroll
                for (int j = 0; j < 8; ++j)
                    s_ += qreg[j] * bf16_to_f32(a[j]) + qreg[8 + j] * bf16_to_f32(b_[j]);
                s_ *= 0.25f;
                p[k] = s_;
                if (k <= q) mmax = fmaxf(mmax, s_);
            }
            float den = 0.f;
            #pragma unroll
            for (int k = 0; k < 32; ++k) {
                float e = (k <= q) ? __expf(p[k] - mmax) : 0.f;
                p[k] = e; den += e;
            }
            float rd = 1.f / den;
            float ctx[16];
            #pragma unroll
            for (int j = 0; j < 16; ++j) ctx[j] = 0.f;
            #pragma unroll
            for (int k = 0; k < 32; ++k) {
                int rk = s * 32 + k;
                int vb0 = (rk * 256 + hd * 32) ^ swzB(rk);
                int vb1 = (rk * 256 + hd * 32 + 16) ^ swzB(rk);
                u16x8 a = *(const u16x8*)(Vc + vb0);
                u16x8 b_ = *(const u16x8*)(Vc + vb1);
                float pk_ = p[k];
                #pragma unroll
                for (int j = 0; j < 8; ++j) { ctx[j] += pk_ * bf16_to_f32(a[j]); ctx[8 + j] += pk_ * bf16_to_f32(b_[j]); }
            }
            u16x8 o0, o1;
            #pragma unroll
            for (int j = 0; j < 8; ++j) { o0[j] = f32_to_bf16(ctx[j] * rd); o1[j] = f32_to_bf16(ctx[8 + j] * rd); }
            *(u16x8*)((char*)Qb + by0) = o0;
            *(u16x8*)((char*)Qb + by1) = o1;
        }
    }
    __syncthreads();

    // ---- P4: X1 = ctx @ Wo + bo + X(reload) -> X1b bf16 (overlays K|V) ----
    {
        u16x8 afr[4][4];
        #pragma unroll
        for (int mt = 0; mt < 4; ++mt)
            #pragma unroll
            for (int kk = 0; kk < 4; ++kk)
                afr[mt][kk] = ldsA256(Qb, mt * 16 + lr, kk * 32 + lh * 8);
        #pragma unroll 1
        for (int i = 0; i < 4; ++i) {
            int nt = wv * 4 + i;
            u16x8 bfr[4];
            #pragma unroll
            for (int kk = 0; kk < 4; ++kk) bfr[kk] = ldgF(WTo, nt * 4 + kk, lane);
            int col = nt * 16 + lr;
            float bc = bo[col];
            #pragma unroll
            for (int mt = 0; mt < 4; ++mt) {
                f32x4 e = Z, o = Z;
                e = mfma16(afr[mt][0], bfr[0], e);
                o = mfma16(afr[mt][1], bfr[1], o);
                e = mfma16(afr[mt][2], bfr[2], e);
                o = mfma16(afr[mt][3], bfr[3], o);
                f32x4 a = e + o;
                #pragma unroll
                for (int reg = 0; reg < 4; ++reg) {
                    int r0 = mt * 16 + lh * 4 + reg;
                    float xv = X[(size_t)(row0 + r0) * EMB + col];
                    *(unsigned short*)((char*)X1b + ((r0 * 512 + col * 2) ^ swzB(r0))) =
                        f32_to_bf16(a[reg] + bc + xv);
                }
            }
        }
    }
    __syncthreads();

    // ---- P5: LN2 from X1b (bf16) -> hbuf ----
    {
        const int r = tid >> 3, sub = tid & 7;
        #pragma unroll 1
        for (int pass = 0; pass < 2; ++pass) {
            int rr = pass * 32 + r;
            float vals[32];
            float s = 0.f, ss = 0.f;
            #pragma unroll
            for (int j = 0; j < 8; ++j) {
                int c = sub * 4 + j * 32;
                u16x4 hv = *(const u16x4*)((const char*)X1b + ((rr * 512 + c * 2) ^ swzB(rr)));
                #pragma unroll
                for (int t = 0; t < 4; ++t) {
                    float f = bf16_to_f32(hv[t]);
                    vals[j * 4 + t] = f;
                    s += f; ss += f * f;
                }
            }
            #pragma unroll
            for (int w = 1; w < 8; w <<= 1) { s += __shfl_xor(s, w, 64); ss += __shfl_xor(ss, w, 64); }
            float mu  = s * (1.f / EMB);
            float inv = rsqrtf(fmaxf(ss * (1.f / EMB) - mu * mu, 0.f) + EPSV);
            #pragma unroll
            for (int j = 0; j < 8; ++j) {
                int c = sub * 4 + j * 32;
                float4 g4 = *(const float4*)&ln_g[c];
                float4 b4 = *(const float4*)&ln_b[c];
                u16x4 pk;
                pk[0] = f32_to_bf16((vals[j * 4 + 0] - mu) * inv * g4.x + b4.x);
                pk[1] = f32_to_bf16((vals[j * 4 + 1] - mu) * inv * g4.y + b4.y);
                pk[2] = f32_to_bf16((vals[j * 4 + 2] - mu) * inv * g4.z + b4.z);
                pk[3] = f32_to_bf16((vals[j * 4 + 3] - mu) * inv * g4.w + b4.w);
                *(u16x4*)((char*)hbuf + ((rr * 512 + c * 2) ^ swzB(rr))) = pk;
            }
        }
    }
    __syncthreads();

    // ---- P6: FFN in 8 chunks of 128 FF cols. fch overlays Q. acc2 persistent ----
    {
        f32x4 acc2[4][4];
        #pragma unroll
        for (int mt = 0; mt < 4; ++mt)
            #pragma unroll
            for (int i = 0; i < 4; ++i) acc2[mt][i] = Z;

        #pragma unroll 1
        for (int ch = 0; ch < 8; ++ch) {
            // FFN1: relu(h2 @ W1[:, chunk] + b1) -> fch.  wave: 2 fn of 8.
            #pragma unroll 1
            for (int mtp = 0; mtp < 4; mtp += 2) {
                u16x8 afr[2][8];
                #pragma unroll
                for (int m = 0; m < 2; ++m)
                    #pragma unroll
                    for (int kk = 0; kk < 8; ++kk)
                        afr[m][kk] = ldsA512(hbuf, (mtp + m) * 16 + lr, kk * 32 + lh * 8);
                #pragma unroll
                for (int f = 0; f < 2; ++f) {
                    int fn = ch * 8 + wv * 2 + f;
                    u16x8 bAll[8];
                    #pragma unroll
                    for (int kk = 0; kk < 8; ++kk) bAll[kk] = ldgF(WT1, fn * 8 + kk, lane);
                    float bc = b1[fn * 16 + lr];
                    int cc = (wv * 2 + f) * 16 + lr;
                    #pragma unroll
                    for (int m = 0; m < 2; ++m) {
                        f32x4 e = Z, o = Z;
                        #pragma unroll
                        for (int kk = 0; kk < 8; kk += 2) {
                            e = mfma16(afr[m][kk], bAll[kk], e);
                            o = mfma16(afr[m][kk + 1], bAll[kk + 1], o);
                        }
                        f32x4 a = e + o;
                        #pragma unroll
                        for (int reg = 0; reg < 4; ++reg) {
                            int r0 = (mtp + m) * 16 + lh * 4 + reg;
                            *(unsigned short*)((char*)fch + ((r0 * 256 + cc * 2) ^ swzB(r0))) =
                                f32_to_bf16(fmaxf(a[reg] + bc, 0.f));
                        }
                    }
                }
            }
            __syncthreads();
            // FFN2: acc2 += fch @ W2[chunk-slice].  wave: 4 nt of 16.
            u16x8 b2f[4][4];
            #pragma unroll
            for (int i = 0; i < 4; ++i)
                #pragma unroll
                for (int kk = 0; kk < 4; ++kk)
                    b2f[i][kk] = ldgF(WT2, (wv * 4 + i) * 32 + ch * 4 + kk, lane);
            #pragma unroll
            for (int mt = 0; mt < 4; ++mt) {
                u16x8 afr[4];
                #pragma unroll
                for (int kk = 0; kk < 4; ++kk)
                    afr[kk] = ldsA256(fch, mt * 16 + lr, kk * 32 + lh * 8);
                #pragma unroll
                for (int i = 0; i < 4; ++i) {
                    f32x4 t = acc2[mt][i];
                    t = mfma16(afr[0], b2f[i][0], t);
                    t = mfma16(afr[1], b2f[i][1], t);
                    t = mfma16(afr[2], b2f[i][2], t);
                    t = mfma16(afr[3], b2f[i][3], t);
                    acc2[mt][i] = t;
                }
            }
            __syncthreads();
        }
        // epilogue: out = acc2 + b2 + X1 (from LDS bf16)
        float* outp = out + (size_t)row0 * EMB;
        #pragma unroll
        for (int i = 0; i < 4; ++i) {
            int col = (wv * 4 + i) * 16 + lr;
            float bc = b2[col];
            #pragma unroll
            for (int mt = 0; mt < 4; ++mt) {
                #pragma unroll
                for (int reg = 0; reg < 4; ++reg) {
                    int r0 = mt * 16 + lh * 4 + reg;
                    float x1 = bf16_to_f32(*(const unsigned short*)((const char*)X1b +
                                          ((r0 * 512 + col * 2) ^ swzB(r0))));
                    outp[(size_t)r0 * EMB + col] = acc2[mt][i][reg] + bc + x1;
                }
            }
        }
    }
}

extern "C" void kernel_launch(void* const* d_in, const int* in_sizes, int n_in,
                              void* d_out, int out_size, void* d_ws, size_t ws_size,
                              hipStream_t stream) {
    const float* X    = (const float*)d_in[0];
    const float* ln_g = (const float*)d_in[1];
    const float* ln_b = (const float*)d_in[2];
    const float* Wq   = (const float*)d_in[3];
    const float* bq   = (const float*)d_in[4];
    const float* Wk   = (const float*)d_in[5];
    const float* bk   = (const float*)d_in[6];
    const float* Wv   = (const float*)d_in[7];
    const float* bv   = (const float*)d_in[8];
    const float* Wo   = (const float*)d_in[9];
    const float* bo   = (const float*)d_in[10];
    const float* W1   = (const float*)d_in[11];
    const float* b1   = (const float*)d_in[12];
    const float* W2   = (const float*)d_in[13];
    const float* b2   = (const float*)d_in[14];
    unsigned short* ws = (unsigned short*)d_ws;
    float* O = (float*)d_out;

    wconv<<<2560, 256, 0, stream>>>(Wq, Wk, Wv, Wo, W1, W2, ws);
    attn_block_mfma<<<2048, 256, 0, stream>>>(X, ln_g, ln_b, bq, bk, bv, bo, b1, b2, ws, O);
}